// Round 1
// baseline (1255.954 us; speedup 1.0000x reference)
//
#include <hip/hip_runtime.h>

#define N_USERS 40000
#define N_ITEMS 20000
#define N_TOTAL (N_USERS + N_ITEMS)
#define D 64

// ---------------- CSR construction ----------------

// u_idx is sorted -> row_ptr via binary search (lower_bound), no atomics.
__global__ void rowptr_u_kernel(const int* __restrict__ u_idx, int* __restrict__ pu, int nnz) {
    int u = blockIdx.x * blockDim.x + threadIdx.x;
    if (u > N_USERS) return;
    int lo = 0, hi = nnz;
    while (lo < hi) { int mid = (lo + hi) >> 1; if (u_idx[mid] < u) lo = mid + 1; else hi = mid; }
    pu[u] = lo;
}

__global__ void count_i_kernel(const int* __restrict__ i_idx, int* __restrict__ cnt, int nnz) {
    int e = blockIdx.x * blockDim.x + threadIdx.x;
    if (e >= nnz) return;
    atomicAdd(cnt + i_idx[e], 1);
}

// single-block exclusive scan of cnt[0..n) -> rptr[0..n], rptr[n] = total
__global__ void scan_i_kernel(const int* __restrict__ cnt, int* __restrict__ rptr, int n) {
    __shared__ int partial[1024];
    int t = threadIdx.x;
    const int CH = (n + 1023) / 1024;
    int start = t * CH, end = min(start + CH, n);
    int s = 0;
    for (int k = start; k < end; ++k) s += cnt[k];
    partial[t] = s;
    __syncthreads();
    for (int off = 1; off < 1024; off <<= 1) {
        int v = (t >= off) ? partial[t - off] : 0;
        __syncthreads();
        partial[t] += v;
        __syncthreads();
    }
    int run = (t == 0) ? 0 : partial[t - 1];
    for (int k = start; k < end; ++k) { rptr[k] = run; run += cnt[k]; }
    if (t == 1023) rptr[n] = partial[1023];
}

__global__ void fill_i_kernel(const int* __restrict__ i_idx, const int* __restrict__ pi,
                              int* __restrict__ fill, int* __restrict__ eids, int nnz) {
    int e = blockIdx.x * blockDim.x + threadIdx.x;
    if (e >= nnz) return;
    int i = i_idx[e];
    int pos = atomicAdd(fill + i, 1);
    eids[pi[i] + pos] = e;
}

// ---------------- embeddings ----------------

// wave per row: user rows sum user_linear[i_idx[e]], item rows sum item_linear[u_idx[e]]
__global__ void emb_kernel(const float* __restrict__ user_linear, const float* __restrict__ item_linear,
                           const int* __restrict__ u_idx, const int* __restrict__ i_idx,
                           const int* __restrict__ pu, const int* __restrict__ pi,
                           const int* __restrict__ eids, float* __restrict__ emb) {
    int wid = (blockIdx.x * blockDim.x + threadIdx.x) >> 6;
    int lane = threadIdx.x & 63;
    if (wid >= N_TOTAL) return;
    float s = 0.f;
    if (wid < N_USERS) {
        int b = pu[wid], e = pu[wid + 1];
        for (int k = b; k < e; ++k) s += user_linear[i_idx[k] * D + lane];
    } else {
        int i = wid - N_USERS;
        int b = pi[i], e = pi[i + 1];
        for (int k = b; k < e; ++k) { int ed = eids[k]; s += item_linear[u_idx[ed] * D + lane]; }
    }
    emb[wid * D + lane] = s;
}

__global__ void invnorm_kernel(const float* __restrict__ emb, float* __restrict__ invn) {
    int wid = (blockIdx.x * blockDim.x + threadIdx.x) >> 6;
    int lane = threadIdx.x & 63;
    if (wid >= N_TOTAL) return;
    float x = emb[wid * D + lane];
    float s = x * x;
    for (int m = 1; m < 64; m <<= 1) s += __shfl_xor(s, m, 64);
    if (lane == 0) {
        float nrm = sqrtf(s);
        invn[wid] = 1.f / fmaxf(nrm, 1e-8f);
    }
}

// wave per edge: cosine sim -> sim_value = (cos+1)/2
__global__ void sims_kernel(const float* __restrict__ emb, const float* __restrict__ invn,
                            const int* __restrict__ u_idx, const int* __restrict__ i_idx,
                            float* __restrict__ sims, int nnz) {
    int wid = (blockIdx.x * blockDim.x + threadIdx.x) >> 6;
    int lane = threadIdx.x & 63;
    if (wid >= nnz) return;
    int u = u_idx[wid], i = i_idx[wid];
    float a = emb[u * D + lane];
    float b = emb[(N_USERS + i) * D + lane];
    float d = a * b;
    for (int m = 1; m < 64; m <<= 1) d += __shfl_xor(d, m, 64);
    if (lane == 0) {
        float sv = (d * invn[u] * invn[N_USERS + i] + 1.f) * 0.5f;
        sims[wid] = sv;
    }
}

// per-row sum of sim values (degree-weighted diag)
__global__ void diag_kernel(const float* __restrict__ sims, const int* __restrict__ pu,
                            const int* __restrict__ pi, const int* __restrict__ eids,
                            float* __restrict__ diag) {
    int r = blockIdx.x * blockDim.x + threadIdx.x;
    if (r >= N_TOTAL) return;
    float s = 0.f;
    if (r < N_USERS) {
        for (int k = pu[r]; k < pu[r + 1]; ++k) s += sims[k];
    } else {
        int i = r - N_USERS;
        for (int k = pi[i]; k < pi[i + 1]; ++k) s += sims[eids[k]];
    }
    diag[r] = s;
}

// ---------------- propagation ----------------

// wave per row: next[r] = (1/(diag+1e-7)) * sum_e sv[e]*cur[col(e)]; acc += next
__global__ void prop_kernel(const float* __restrict__ cur, float* __restrict__ next,
                            float* __restrict__ acc, const float* __restrict__ sims,
                            const float* __restrict__ diag,
                            const int* __restrict__ u_idx, const int* __restrict__ i_idx,
                            const int* __restrict__ pu, const int* __restrict__ pi,
                            const int* __restrict__ eids) {
    int wid = (blockIdx.x * blockDim.x + threadIdx.x) >> 6;
    int lane = threadIdx.x & 63;
    if (wid >= N_TOTAL) return;
    float s = 0.f;
    float invd = 1.f / (diag[wid] + 1e-7f);
    if (wid < N_USERS) {
        int b = pu[wid], e = pu[wid + 1];
        for (int k = b; k < e; ++k) {
            int col = N_USERS + i_idx[k];
            s += sims[k] * cur[col * D + lane];
        }
    } else {
        int i = wid - N_USERS;
        int b = pi[i], e = pi[i + 1];
        for (int k = b; k < e; ++k) {
            int ed = eids[k];
            s += sims[ed] * cur[u_idx[ed] * D + lane];
        }
    }
    float v = s * invd;
    next[wid * D + lane] = v;
    acc[wid * D + lane] += v;
}

__global__ void copy4_kernel(const float4* __restrict__ src, float4* __restrict__ dst, int n4) {
    int t = blockIdx.x * blockDim.x + threadIdx.x;
    if (t < n4) dst[t] = src[t];
}

__global__ void scale_kernel(float* __restrict__ p, float f, int n) {
    int t = blockIdx.x * blockDim.x + threadIdx.x;
    if (t < n) p[t] *= f;
}

// ---------------- launch ----------------

extern "C" void kernel_launch(void* const* d_in, const int* in_sizes, int n_in,
                              void* d_out, int out_size, void* d_ws, size_t ws_size,
                              hipStream_t stream) {
    const float* user_linear = (const float*)d_in[0];
    const float* item_linear = (const float*)d_in[1];
    const int* u_idx = (const int*)d_in[2];
    const int* i_idx = (const int*)d_in[3];
    const int nnz = in_sizes[2];

    // carve workspace (256B aligned)
    char* p = (char*)d_ws;
    auto carve = [&](size_t bytes) { void* r = (void*)p; p += (bytes + 255) & ~(size_t)255; return r; };
    float* embA = (float*)carve((size_t)N_TOTAL * D * 4);
    float* embB = (float*)carve((size_t)N_TOTAL * D * 4);
    float* sims = (float*)carve((size_t)nnz * 4);
    float* diag = (float*)carve((size_t)N_TOTAL * 4);
    float* invn = (float*)carve((size_t)N_TOTAL * 4);
    int* pu = (int*)carve((size_t)(N_USERS + 1) * 4);
    int* pi = (int*)carve((size_t)(N_ITEMS + 1) * 4);
    int* eids = (int*)carve((size_t)nnz * 4);
    int* cnt = (int*)carve((size_t)N_ITEMS * 4);

    float* acc = (float*)d_out;  // [N_TOTAL, D]

    const int B = 256;

    // CSR build
    hipMemsetAsync(cnt, 0, (size_t)N_ITEMS * 4, stream);
    rowptr_u_kernel<<<(N_USERS + 1 + B - 1) / B, B, 0, stream>>>(u_idx, pu, nnz);
    count_i_kernel<<<(nnz + B - 1) / B, B, 0, stream>>>(i_idx, cnt, nnz);
    scan_i_kernel<<<1, 1024, 0, stream>>>(cnt, pi, N_ITEMS);
    hipMemsetAsync(cnt, 0, (size_t)N_ITEMS * 4, stream);
    fill_i_kernel<<<(nnz + B - 1) / B, B, 0, stream>>>(i_idx, pi, cnt, eids, nnz);

    // embeddings + sims + diag
    int rowWaveThreads = N_TOTAL * 64;
    emb_kernel<<<(rowWaveThreads + B - 1) / B, B, 0, stream>>>(user_linear, item_linear, u_idx, i_idx,
                                                              pu, pi, eids, embA);
    invnorm_kernel<<<(rowWaveThreads + B - 1) / B, B, 0, stream>>>(embA, invn);
    long long simThreads = (long long)nnz * 64;
    sims_kernel<<<(int)((simThreads + B - 1) / B), B, 0, stream>>>(embA, invn, u_idx, i_idx, sims, nnz);
    diag_kernel<<<(N_TOTAL + B - 1) / B, B, 0, stream>>>(sims, pu, pi, eids, diag);

    // acc = emb0
    int n4 = N_TOTAL * D / 4;
    copy4_kernel<<<(n4 + B - 1) / B, B, 0, stream>>>((const float4*)embA, (float4*)acc, n4);

    // 3 propagation layers, acc += each
    prop_kernel<<<(rowWaveThreads + B - 1) / B, B, 0, stream>>>(embA, embB, acc, sims, diag,
                                                               u_idx, i_idx, pu, pi, eids);
    prop_kernel<<<(rowWaveThreads + B - 1) / B, B, 0, stream>>>(embB, embA, acc, sims, diag,
                                                               u_idx, i_idx, pu, pi, eids);
    prop_kernel<<<(rowWaveThreads + B - 1) / B, B, 0, stream>>>(embA, embB, acc, sims, diag,
                                                               u_idx, i_idx, pu, pi, eids);

    // mean over 4
    int nTot = N_TOTAL * D;
    scale_kernel<<<(nTot + B - 1) / B, B, 0, stream>>>(acc, 0.25f, nTot);
}

// Round 2
// 568.906 us; speedup vs baseline: 2.2077x; 2.2077x over previous
//
#include <hip/hip_runtime.h>

#define N_USERS 40000
#define N_ITEMS 20000
#define N_TOTAL (N_USERS + N_ITEMS)
#define D 64

// ---------------- CSR construction ----------------

// u_idx is sorted -> row_ptr via binary search (lower_bound), no atomics.
__global__ void rowptr_u_kernel(const int* __restrict__ u_idx, int* __restrict__ pu, int nnz) {
    int u = blockIdx.x * blockDim.x + threadIdx.x;
    if (u > N_USERS) return;
    int lo = 0, hi = nnz;
    while (lo < hi) { int mid = (lo + hi) >> 1; if (u_idx[mid] < u) lo = mid + 1; else hi = mid; }
    pu[u] = lo;
}

__global__ void count_i_kernel(const int* __restrict__ i_idx, int* __restrict__ cnt, int nnz) {
    int e = blockIdx.x * blockDim.x + threadIdx.x;
    if (e >= nnz) return;
    atomicAdd(cnt + i_idx[e], 1);
}

// single-block exclusive scan of cnt[0..n) -> rptr[0..n], rptr[n] = total
__global__ void scan_i_kernel(const int* __restrict__ cnt, int* __restrict__ rptr, int n) {
    __shared__ int partial[1024];
    int t = threadIdx.x;
    const int CH = (n + 1023) / 1024;
    int start = t * CH, end = min(start + CH, n);
    int s = 0;
    for (int k = start; k < end; ++k) s += cnt[k];
    partial[t] = s;
    __syncthreads();
    for (int off = 1; off < 1024; off <<= 1) {
        int v = (t >= off) ? partial[t - off] : 0;
        __syncthreads();
        partial[t] += v;
        __syncthreads();
    }
    int run = (t == 0) ? 0 : partial[t - 1];
    for (int k = start; k < end; ++k) { rptr[k] = run; run += cnt[k]; }
    if (t == 1023) rptr[n] = partial[1023];
}

__global__ void fill_i_kernel(const int* __restrict__ i_idx, const int* __restrict__ pi,
                              int* __restrict__ fill, int* __restrict__ eids, int nnz) {
    int e = blockIdx.x * blockDim.x + threadIdx.x;
    if (e >= nnz) return;
    int i = i_idx[e];
    int pos = atomicAdd(fill + i, 1);
    eids[pi[i] + pos] = e;
}

// col2[j] = u_idx[eids[j]] (contiguous cols for the item side)
__global__ void gatherc_kernel(const int* __restrict__ eids, const int* __restrict__ u_idx,
                               int* __restrict__ col2, int nnz) {
    int t = blockIdx.x * blockDim.x + threadIdx.x;
    if (t < nnz) col2[t] = u_idx[eids[t]];
}

// w2[j] = sims[eids[j]] (contiguous weights for the item side)
__global__ void gatherw_kernel(const int* __restrict__ eids, const float* __restrict__ sims,
                               float* __restrict__ w2, int nnz) {
    int t = blockIdx.x * blockDim.x + threadIdx.x;
    if (t < nnz) w2[t] = sims[eids[t]];
}

// ---------------- embeddings (fused: emb + acc init + invnorm) ----------------
// wave per row; 4 edge-groups x 16 lanes x float4
__global__ void emb_kernel(const float* __restrict__ user_linear, const float* __restrict__ item_linear,
                           const int* __restrict__ i_idx, const int* __restrict__ col2,
                           const int* __restrict__ pu, const int* __restrict__ pi,
                           float* __restrict__ emb, float* __restrict__ acc,
                           float* __restrict__ invn) {
    int wid = (blockIdx.x * blockDim.x + threadIdx.x) >> 6;
    int lane = threadIdx.x & 63;
    if (wid >= N_TOTAL) return;
    int g = lane >> 4, c = lane & 15;
    float4 s = make_float4(0.f, 0.f, 0.f, 0.f);
    if (wid < N_USERS) {
        int b = pu[wid], e = pu[wid + 1];
        for (int k = b + g; k < e; k += 4) {
            float4 v = ((const float4*)(user_linear + (size_t)i_idx[k] * D))[c];
            s.x += v.x; s.y += v.y; s.z += v.z; s.w += v.w;
        }
    } else {
        int i = wid - N_USERS;
        int b = pi[i], e = pi[i + 1];
        for (int k = b + g; k < e; k += 4) {
            float4 v = ((const float4*)(item_linear + (size_t)col2[k] * D))[c];
            s.x += v.x; s.y += v.y; s.z += v.z; s.w += v.w;
        }
    }
    // reduce across the 4 edge-groups (lane bits 4,5)
    for (int m = 16; m < 64; m <<= 1) {
        s.x += __shfl_xor(s.x, m, 64);
        s.y += __shfl_xor(s.y, m, 64);
        s.z += __shfl_xor(s.z, m, 64);
        s.w += __shfl_xor(s.w, m, 64);
    }
    // row norm: reduce sumsq across the 16 column lanes (bits 0..3)
    float nsq = s.x * s.x + s.y * s.y + s.z * s.z + s.w * s.w;
    for (int m = 1; m < 16; m <<= 1) nsq += __shfl_xor(nsq, m, 64);
    if (g == 0) {
        ((float4*)(emb + (size_t)wid * D))[c] = s;
        ((float4*)(acc + (size_t)wid * D))[c] = s;  // layer-0 contribution
        if (c == 0) invn[wid] = 1.f / fmaxf(sqrtf(nsq), 1e-8f);
    }
}

// ---------------- sims (fused: cosine sim + diag atomics) ----------------
// wave handles 4 edges; 16 lanes x float4 per edge
__global__ void sims_kernel(const float* __restrict__ emb, const float* __restrict__ invn,
                            const int* __restrict__ u_idx, const int* __restrict__ i_idx,
                            float* __restrict__ sims, float* __restrict__ diag, int nnz) {
    int wid = (blockIdx.x * blockDim.x + threadIdx.x) >> 6;
    int lane = threadIdx.x & 63;
    int g = lane >> 4, c = lane & 15;
    int e0 = wid * 4 + g;
    if (e0 >= nnz) return;
    int u = u_idx[e0], i = i_idx[e0];
    float4 a = ((const float4*)(emb + (size_t)u * D))[c];
    float4 b = ((const float4*)(emb + (size_t)(N_USERS + i) * D))[c];
    float d = a.x * b.x + a.y * b.y + a.z * b.z + a.w * b.w;
    for (int m = 1; m < 16; m <<= 1) d += __shfl_xor(d, m, 64);
    if (c == 0) {
        float sv = (d * invn[u] * invn[N_USERS + i] + 1.f) * 0.5f;
        sims[e0] = sv;
        atomicAdd(diag + u, sv);
        atomicAdd(diag + N_USERS + i, sv);
    }
}

// ---------------- propagation ----------------
// wave per row; 4 edge-groups x 16 lanes x float4; FINAL fuses the /4 mean
template <bool FINAL>
__global__ void prop_kernel(const float* __restrict__ cur, float* __restrict__ next,
                            float* __restrict__ acc, const float* __restrict__ sims,
                            const float* __restrict__ w2, const float* __restrict__ diag,
                            const int* __restrict__ i_idx, const int* __restrict__ col2,
                            const int* __restrict__ pu, const int* __restrict__ pi) {
    int wid = (blockIdx.x * blockDim.x + threadIdx.x) >> 6;
    int lane = threadIdx.x & 63;
    if (wid >= N_TOTAL) return;
    int g = lane >> 4, c = lane & 15;
    float4 s = make_float4(0.f, 0.f, 0.f, 0.f);
    if (wid < N_USERS) {
        int b = pu[wid], e = pu[wid + 1];
        for (int k = b + g; k < e; k += 4) {
            float w = sims[k];
            float4 v = ((const float4*)(cur + (size_t)(N_USERS + i_idx[k]) * D))[c];
            s.x += w * v.x; s.y += w * v.y; s.z += w * v.z; s.w += w * v.w;
        }
    } else {
        int i = wid - N_USERS;
        int b = pi[i], e = pi[i + 1];
        for (int k = b + g; k < e; k += 4) {
            float w = w2[k];
            float4 v = ((const float4*)(cur + (size_t)col2[k] * D))[c];
            s.x += w * v.x; s.y += w * v.y; s.z += w * v.z; s.w += w * v.w;
        }
    }
    for (int m = 16; m < 64; m <<= 1) {
        s.x += __shfl_xor(s.x, m, 64);
        s.y += __shfl_xor(s.y, m, 64);
        s.z += __shfl_xor(s.z, m, 64);
        s.w += __shfl_xor(s.w, m, 64);
    }
    if (g == 0) {
        float invd = 1.f / (diag[wid] + 1e-7f);
        float4 v = make_float4(s.x * invd, s.y * invd, s.z * invd, s.w * invd);
        float4* ap = (float4*)(acc + (size_t)wid * D);
        float4 a = ap[c];
        if (FINAL) {
            a.x = (a.x + v.x) * 0.25f; a.y = (a.y + v.y) * 0.25f;
            a.z = (a.z + v.z) * 0.25f; a.w = (a.w + v.w) * 0.25f;
            ap[c] = a;
        } else {
            ((float4*)(next + (size_t)wid * D))[c] = v;
            a.x += v.x; a.y += v.y; a.z += v.z; a.w += v.w;
            ap[c] = a;
        }
    }
}

// ---------------- launch ----------------

extern "C" void kernel_launch(void* const* d_in, const int* in_sizes, int n_in,
                              void* d_out, int out_size, void* d_ws, size_t ws_size,
                              hipStream_t stream) {
    const float* user_linear = (const float*)d_in[0];
    const float* item_linear = (const float*)d_in[1];
    const int* u_idx = (const int*)d_in[2];
    const int* i_idx = (const int*)d_in[3];
    const int nnz = in_sizes[2];

    // carve workspace (256B aligned)
    char* p = (char*)d_ws;
    auto carve = [&](size_t bytes) { void* r = (void*)p; p += (bytes + 255) & ~(size_t)255; return r; };
    float* embA = (float*)carve((size_t)N_TOTAL * D * 4);
    float* embB = (float*)carve((size_t)N_TOTAL * D * 4);
    float* sims = (float*)carve((size_t)nnz * 4);
    float* w2   = (float*)carve((size_t)nnz * 4);
    float* diag = (float*)carve((size_t)N_TOTAL * 4);
    float* invn = (float*)carve((size_t)N_TOTAL * 4);
    int* pu   = (int*)carve((size_t)(N_USERS + 1) * 4);
    int* pi   = (int*)carve((size_t)(N_ITEMS + 1) * 4);
    int* eids = (int*)carve((size_t)nnz * 4);
    int* col2 = (int*)carve((size_t)nnz * 4);
    int* cnt  = (int*)carve((size_t)N_ITEMS * 4);

    float* acc = (float*)d_out;  // [N_TOTAL, D]

    const int B = 256;

    // CSR build
    hipMemsetAsync(cnt, 0, (size_t)N_ITEMS * 4, stream);
    hipMemsetAsync(diag, 0, (size_t)N_TOTAL * 4, stream);
    rowptr_u_kernel<<<(N_USERS + 1 + B - 1) / B, B, 0, stream>>>(u_idx, pu, nnz);
    count_i_kernel<<<(nnz + B - 1) / B, B, 0, stream>>>(i_idx, cnt, nnz);
    scan_i_kernel<<<1, 1024, 0, stream>>>(cnt, pi, N_ITEMS);
    hipMemsetAsync(cnt, 0, (size_t)N_ITEMS * 4, stream);
    fill_i_kernel<<<(nnz + B - 1) / B, B, 0, stream>>>(i_idx, pi, cnt, eids, nnz);
    gatherc_kernel<<<(nnz + B - 1) / B, B, 0, stream>>>(eids, u_idx, col2, nnz);

    // embeddings (+acc init, +invnorm)
    int rowWaveThreads = N_TOTAL * 64;
    emb_kernel<<<(rowWaveThreads + B - 1) / B, B, 0, stream>>>(user_linear, item_linear, i_idx, col2,
                                                              pu, pi, embA, acc, invn);

    // sims (+diag)
    long long simWaves = (nnz + 3) / 4;
    long long simThreads = simWaves * 64;
    sims_kernel<<<(int)((simThreads + B - 1) / B), B, 0, stream>>>(embA, invn, u_idx, i_idx,
                                                                  sims, diag, nnz);
    gatherw_kernel<<<(nnz + B - 1) / B, B, 0, stream>>>(eids, sims, w2, nnz);

    // 3 propagation layers; final one folds the mean (x0.25)
    prop_kernel<false><<<(rowWaveThreads + B - 1) / B, B, 0, stream>>>(embA, embB, acc, sims, w2, diag,
                                                                      i_idx, col2, pu, pi);
    prop_kernel<false><<<(rowWaveThreads + B - 1) / B, B, 0, stream>>>(embB, embA, acc, sims, w2, diag,
                                                                      i_idx, col2, pu, pi);
    prop_kernel<true><<<(rowWaveThreads + B - 1) / B, B, 0, stream>>>(embA, embB, acc, sims, w2, diag,
                                                                     i_idx, col2, pu, pi);
}

// Round 3
// 431.963 us; speedup vs baseline: 2.9076x; 1.3170x over previous
//
#include <hip/hip_runtime.h>

#define N_USERS 40000
#define N_ITEMS 20000
#define N_TOTAL (N_USERS + N_ITEMS)
#define D 64

// ---------------- CSR construction ----------------

// u_idx is sorted -> row_ptr via binary search (lower_bound), no atomics.
__global__ void rowptr_u_kernel(const int* __restrict__ u_idx, int* __restrict__ pu, int nnz) {
    int u = blockIdx.x * blockDim.x + threadIdx.x;
    if (u > N_USERS) return;
    int lo = 0, hi = nnz;
    while (lo < hi) { int mid = (lo + hi) >> 1; if (u_idx[mid] < u) lo = mid + 1; else hi = mid; }
    pu[u] = lo;
}

__global__ void count_i_kernel(const int* __restrict__ i_idx, int* __restrict__ cnt, int nnz) {
    int e = blockIdx.x * blockDim.x + threadIdx.x;
    if (e >= nnz) return;
    atomicAdd(cnt + i_idx[e], 1);
}

// single-block exclusive scan of cnt[0..n) -> rptr[0..n], rptr[n] = total
__global__ void scan_i_kernel(const int* __restrict__ cnt, int* __restrict__ rptr, int n) {
    __shared__ int partial[1024];
    int t = threadIdx.x;
    const int CH = (n + 1023) / 1024;
    int start = t * CH, end = min(start + CH, n);
    int s = 0;
    for (int k = start; k < end; ++k) s += cnt[k];
    partial[t] = s;
    __syncthreads();
    for (int off = 1; off < 1024; off <<= 1) {
        int v = (t >= off) ? partial[t - off] : 0;
        __syncthreads();
        partial[t] += v;
        __syncthreads();
    }
    int run = (t == 0) ? 0 : partial[t - 1];
    for (int k = start; k < end; ++k) { rptr[k] = run; run += cnt[k]; }
    if (t == 1023) rptr[n] = partial[1023];
}

__global__ void fill_i_kernel(const int* __restrict__ i_idx, const int* __restrict__ pi,
                              int* __restrict__ fill, int* __restrict__ eids, int nnz) {
    int e = blockIdx.x * blockDim.x + threadIdx.x;
    if (e >= nnz) return;
    int i = i_idx[e];
    int pos = atomicAdd(fill + i, 1);
    eids[pi[i] + pos] = e;
}

// col2[j] = u_idx[eids[j]] (contiguous cols for the item side)
__global__ void gatherc_kernel(const int* __restrict__ eids, const int* __restrict__ u_idx,
                               int* __restrict__ col2, int nnz) {
    int t = blockIdx.x * blockDim.x + threadIdx.x;
    if (t < nnz) col2[t] = u_idx[eids[t]];
}

// w2[j] = sims[eids[j]] (contiguous weights for the item side)
__global__ void gatherw_kernel(const int* __restrict__ eids, const float* __restrict__ sims,
                               float* __restrict__ w2, int nnz) {
    int t = blockIdx.x * blockDim.x + threadIdx.x;
    if (t < nnz) w2[t] = sims[eids[t]];
}

// item-side diag: contiguous row-sum of w2 (no atomics)
__global__ void diagi_kernel(const float* __restrict__ w2, const int* __restrict__ pi,
                             float* __restrict__ diag) {
    int i = blockIdx.x * blockDim.x + threadIdx.x;
    if (i >= N_ITEMS) return;
    float s = 0.f;
    int e = pi[i + 1];
    for (int k = pi[i]; k < e; ++k) s += w2[k];
    diag[N_USERS + i] = s;
}

// ---------------- embeddings (fused: emb + acc init + invnorm) ----------------
// wave per row; 4 edge-groups x 16 lanes x float4; 2-way unrolled
__global__ void emb_kernel(const float* __restrict__ user_linear, const float* __restrict__ item_linear,
                           const int* __restrict__ i_idx, const int* __restrict__ col2,
                           const int* __restrict__ pu, const int* __restrict__ pi,
                           float* __restrict__ emb, float* __restrict__ acc,
                           float* __restrict__ invn) {
    int wid = (blockIdx.x * blockDim.x + threadIdx.x) >> 6;
    int lane = threadIdx.x & 63;
    if (wid >= N_TOTAL) return;
    int g = lane >> 4, c = lane & 15;
    float4 s0 = make_float4(0.f, 0.f, 0.f, 0.f);
    float4 s1 = make_float4(0.f, 0.f, 0.f, 0.f);
    if (wid < N_USERS) {
        int b = pu[wid], e = pu[wid + 1];
        int k = b + g;
        for (; k + 4 < e; k += 8) {
            float4 v0 = ((const float4*)(user_linear + (size_t)i_idx[k] * D))[c];
            float4 v1 = ((const float4*)(user_linear + (size_t)i_idx[k + 4] * D))[c];
            s0.x += v0.x; s0.y += v0.y; s0.z += v0.z; s0.w += v0.w;
            s1.x += v1.x; s1.y += v1.y; s1.z += v1.z; s1.w += v1.w;
        }
        if (k < e) {
            float4 v0 = ((const float4*)(user_linear + (size_t)i_idx[k] * D))[c];
            s0.x += v0.x; s0.y += v0.y; s0.z += v0.z; s0.w += v0.w;
        }
    } else {
        int i = wid - N_USERS;
        int b = pi[i], e = pi[i + 1];
        int k = b + g;
        for (; k + 4 < e; k += 8) {
            float4 v0 = ((const float4*)(item_linear + (size_t)col2[k] * D))[c];
            float4 v1 = ((const float4*)(item_linear + (size_t)col2[k + 4] * D))[c];
            s0.x += v0.x; s0.y += v0.y; s0.z += v0.z; s0.w += v0.w;
            s1.x += v1.x; s1.y += v1.y; s1.z += v1.z; s1.w += v1.w;
        }
        if (k < e) {
            float4 v0 = ((const float4*)(item_linear + (size_t)col2[k] * D))[c];
            s0.x += v0.x; s0.y += v0.y; s0.z += v0.z; s0.w += v0.w;
        }
    }
    float4 s = make_float4(s0.x + s1.x, s0.y + s1.y, s0.z + s1.z, s0.w + s1.w);
    // reduce across the 4 edge-groups (lane bits 4,5)
    #pragma unroll
    for (int m = 16; m < 64; m <<= 1) {
        s.x += __shfl_xor(s.x, m, 64);
        s.y += __shfl_xor(s.y, m, 64);
        s.z += __shfl_xor(s.z, m, 64);
        s.w += __shfl_xor(s.w, m, 64);
    }
    // row norm: reduce sumsq across the 16 column lanes (bits 0..3)
    float nsq = s.x * s.x + s.y * s.y + s.z * s.z + s.w * s.w;
    #pragma unroll
    for (int m = 1; m < 16; m <<= 1) nsq += __shfl_xor(nsq, m, 64);
    if (g == 0) {
        ((float4*)(emb + (size_t)wid * D))[c] = s;
        ((float4*)(acc + (size_t)wid * D))[c] = s;  // layer-0 contribution
        if (c == 0) invn[wid] = 1.f / fmaxf(sqrtf(nsq), 1e-8f);
    }
}

// ---------------- sims (wave per user; fused user diag; no atomics) ----------------
__global__ void sims_kernel(const float* __restrict__ emb, const float* __restrict__ invn,
                            const int* __restrict__ i_idx, const int* __restrict__ pu,
                            float* __restrict__ sims, float* __restrict__ diag) {
    int u = (blockIdx.x * blockDim.x + threadIdx.x) >> 6;
    int lane = threadIdx.x & 63;
    if (u >= N_USERS) return;
    int g = lane >> 4, c = lane & 15;
    float invu = invn[u];
    float4 un = ((const float4*)(emb + (size_t)u * D))[c];
    un.x *= invu; un.y *= invu; un.z *= invu; un.w *= invu;
    int b = pu[u], e = pu[u + 1];
    float dsum = 0.f;
    int k = b + g;
    for (; k + 4 < e; k += 8) {
        int i0 = i_idx[k], i1 = i_idx[k + 4];
        float4 v0 = ((const float4*)(emb + (size_t)(N_USERS + i0) * D))[c];
        float4 v1 = ((const float4*)(emb + (size_t)(N_USERS + i1) * D))[c];
        float d0 = un.x * v0.x + un.y * v0.y + un.z * v0.z + un.w * v0.w;
        float d1 = un.x * v1.x + un.y * v1.y + un.z * v1.z + un.w * v1.w;
        #pragma unroll
        for (int m = 1; m < 16; m <<= 1) { d0 += __shfl_xor(d0, m, 64); d1 += __shfl_xor(d1, m, 64); }
        if (c == 0) {
            float sv0 = (d0 * invn[N_USERS + i0] + 1.f) * 0.5f;
            float sv1 = (d1 * invn[N_USERS + i1] + 1.f) * 0.5f;
            sims[k] = sv0; sims[k + 4] = sv1;
            dsum += sv0 + sv1;
        }
    }
    if (k < e) {
        int i0 = i_idx[k];
        float4 v0 = ((const float4*)(emb + (size_t)(N_USERS + i0) * D))[c];
        float d0 = un.x * v0.x + un.y * v0.y + un.z * v0.z + un.w * v0.w;
        #pragma unroll
        for (int m = 1; m < 16; m <<= 1) d0 += __shfl_xor(d0, m, 64);
        if (c == 0) {
            float sv0 = (d0 * invn[N_USERS + i0] + 1.f) * 0.5f;
            sims[k] = sv0;
            dsum += sv0;
        }
    }
    // combine the 4 groups' partials (held on c==0 lanes)
    dsum += __shfl_xor(dsum, 16, 64);
    dsum += __shfl_xor(dsum, 32, 64);
    if (lane == 0) diag[u] = dsum;
}

// ---------------- propagation ----------------
// wave per row; 4 edge-groups x 16 lanes x float4; 2-way unrolled; FINAL fuses the /4 mean
template <bool FINAL>
__global__ void prop_kernel(const float* __restrict__ cur, float* __restrict__ next,
                            float* __restrict__ acc, const float* __restrict__ sims,
                            const float* __restrict__ w2, const float* __restrict__ diag,
                            const int* __restrict__ i_idx, const int* __restrict__ col2,
                            const int* __restrict__ pu, const int* __restrict__ pi) {
    int wid = (blockIdx.x * blockDim.x + threadIdx.x) >> 6;
    int lane = threadIdx.x & 63;
    if (wid >= N_TOTAL) return;
    int g = lane >> 4, c = lane & 15;
    float4 s0 = make_float4(0.f, 0.f, 0.f, 0.f);
    float4 s1 = make_float4(0.f, 0.f, 0.f, 0.f);
    if (wid < N_USERS) {
        int b = pu[wid], e = pu[wid + 1];
        int k = b + g;
        for (; k + 4 < e; k += 8) {
            float w0 = sims[k], w1 = sims[k + 4];
            float4 v0 = ((const float4*)(cur + (size_t)(N_USERS + i_idx[k]) * D))[c];
            float4 v1 = ((const float4*)(cur + (size_t)(N_USERS + i_idx[k + 4]) * D))[c];
            s0.x += w0 * v0.x; s0.y += w0 * v0.y; s0.z += w0 * v0.z; s0.w += w0 * v0.w;
            s1.x += w1 * v1.x; s1.y += w1 * v1.y; s1.z += w1 * v1.z; s1.w += w1 * v1.w;
        }
        if (k < e) {
            float w0 = sims[k];
            float4 v0 = ((const float4*)(cur + (size_t)(N_USERS + i_idx[k]) * D))[c];
            s0.x += w0 * v0.x; s0.y += w0 * v0.y; s0.z += w0 * v0.z; s0.w += w0 * v0.w;
        }
    } else {
        int i = wid - N_USERS;
        int b = pi[i], e = pi[i + 1];
        int k = b + g;
        for (; k + 4 < e; k += 8) {
            float w0 = w2[k], w1 = w2[k + 4];
            float4 v0 = ((const float4*)(cur + (size_t)col2[k] * D))[c];
            float4 v1 = ((const float4*)(cur + (size_t)col2[k + 4] * D))[c];
            s0.x += w0 * v0.x; s0.y += w0 * v0.y; s0.z += w0 * v0.z; s0.w += w0 * v0.w;
            s1.x += w1 * v1.x; s1.y += w1 * v1.y; s1.z += w1 * v1.z; s1.w += w1 * v1.w;
        }
        if (k < e) {
            float w0 = w2[k];
            float4 v0 = ((const float4*)(cur + (size_t)col2[k] * D))[c];
            s0.x += w0 * v0.x; s0.y += w0 * v0.y; s0.z += w0 * v0.z; s0.w += w0 * v0.w;
        }
    }
    float4 s = make_float4(s0.x + s1.x, s0.y + s1.y, s0.z + s1.z, s0.w + s1.w);
    #pragma unroll
    for (int m = 16; m < 64; m <<= 1) {
        s.x += __shfl_xor(s.x, m, 64);
        s.y += __shfl_xor(s.y, m, 64);
        s.z += __shfl_xor(s.z, m, 64);
        s.w += __shfl_xor(s.w, m, 64);
    }
    if (g == 0) {
        float invd = 1.f / (diag[wid] + 1e-7f);
        float4 v = make_float4(s.x * invd, s.y * invd, s.z * invd, s.w * invd);
        float4* ap = (float4*)(acc + (size_t)wid * D);
        float4 a = ap[c];
        if (FINAL) {
            a.x = (a.x + v.x) * 0.25f; a.y = (a.y + v.y) * 0.25f;
            a.z = (a.z + v.z) * 0.25f; a.w = (a.w + v.w) * 0.25f;
            ap[c] = a;
        } else {
            ((float4*)(next + (size_t)wid * D))[c] = v;
            a.x += v.x; a.y += v.y; a.z += v.z; a.w += v.w;
            ap[c] = a;
        }
    }
}

// ---------------- launch ----------------

extern "C" void kernel_launch(void* const* d_in, const int* in_sizes, int n_in,
                              void* d_out, int out_size, void* d_ws, size_t ws_size,
                              hipStream_t stream) {
    const float* user_linear = (const float*)d_in[0];
    const float* item_linear = (const float*)d_in[1];
    const int* u_idx = (const int*)d_in[2];
    const int* i_idx = (const int*)d_in[3];
    const int nnz = in_sizes[2];

    // carve workspace (256B aligned)
    char* p = (char*)d_ws;
    auto carve = [&](size_t bytes) { void* r = (void*)p; p += (bytes + 255) & ~(size_t)255; return r; };
    float* embA = (float*)carve((size_t)N_TOTAL * D * 4);
    float* embB = (float*)carve((size_t)N_TOTAL * D * 4);
    float* sims = (float*)carve((size_t)nnz * 4);
    float* w2   = (float*)carve((size_t)nnz * 4);
    float* diag = (float*)carve((size_t)N_TOTAL * 4);
    float* invn = (float*)carve((size_t)N_TOTAL * 4);
    int* pu   = (int*)carve((size_t)(N_USERS + 1) * 4);
    int* pi   = (int*)carve((size_t)(N_ITEMS + 1) * 4);
    int* eids = (int*)carve((size_t)nnz * 4);
    int* col2 = (int*)carve((size_t)nnz * 4);
    int* cnt  = (int*)carve((size_t)N_ITEMS * 4);

    float* acc = (float*)d_out;  // [N_TOTAL, D]

    const int B = 256;

    // CSR build
    hipMemsetAsync(cnt, 0, (size_t)N_ITEMS * 4, stream);
    rowptr_u_kernel<<<(N_USERS + 1 + B - 1) / B, B, 0, stream>>>(u_idx, pu, nnz);
    count_i_kernel<<<(nnz + B - 1) / B, B, 0, stream>>>(i_idx, cnt, nnz);
    scan_i_kernel<<<1, 1024, 0, stream>>>(cnt, pi, N_ITEMS);
    hipMemsetAsync(cnt, 0, (size_t)N_ITEMS * 4, stream);
    fill_i_kernel<<<(nnz + B - 1) / B, B, 0, stream>>>(i_idx, pi, cnt, eids, nnz);
    gatherc_kernel<<<(nnz + B - 1) / B, B, 0, stream>>>(eids, u_idx, col2, nnz);

    // embeddings (+acc init, +invnorm)
    int rowWaveThreads = N_TOTAL * 64;
    emb_kernel<<<(rowWaveThreads + B - 1) / B, B, 0, stream>>>(user_linear, item_linear, i_idx, col2,
                                                              pu, pi, embA, acc, invn);

    // sims (wave per user; writes user diag) then item diag from w2
    long long simThreads = (long long)N_USERS * 64;
    sims_kernel<<<(int)((simThreads + B - 1) / B), B, 0, stream>>>(embA, invn, i_idx, pu, sims, diag);
    gatherw_kernel<<<(nnz + B - 1) / B, B, 0, stream>>>(eids, sims, w2, nnz);
    diagi_kernel<<<(N_ITEMS + B - 1) / B, B, 0, stream>>>(w2, pi, diag);

    // 3 propagation layers; final one folds the mean (x0.25)
    prop_kernel<false><<<(rowWaveThreads + B - 1) / B, B, 0, stream>>>(embA, embB, acc, sims, w2, diag,
                                                                      i_idx, col2, pu, pi);
    prop_kernel<false><<<(rowWaveThreads + B - 1) / B, B, 0, stream>>>(embB, embA, acc, sims, w2, diag,
                                                                      i_idx, col2, pu, pi);
    prop_kernel<true><<<(rowWaveThreads + B - 1) / B, B, 0, stream>>>(embA, embB, acc, sims, w2, diag,
                                                                     i_idx, col2, pu, pi);
}

// Round 4
// 344.557 us; speedup vs baseline: 3.6451x; 1.2537x over previous
//
#include <hip/hip_runtime.h>
#include <hip/hip_fp16.h>

#define N_USERS 40000
#define N_ITEMS 20000
#define N_TOTAL (N_USERS + N_ITEMS)
#define D 64

union H8 { uint4 u; __half h[8]; };

// ---------------- CSR construction ----------------

__global__ void rowptr_u_kernel(const int* __restrict__ u_idx, int* __restrict__ pu, int nnz) {
    int u = blockIdx.x * blockDim.x + threadIdx.x;
    if (u > N_USERS) return;
    int lo = 0, hi = nnz;
    while (lo < hi) { int mid = (lo + hi) >> 1; if (u_idx[mid] < u) lo = mid + 1; else hi = mid; }
    pu[u] = lo;
}

__global__ void count_i_kernel(const int* __restrict__ i_idx, int* __restrict__ cnt, int nnz) {
    int e = blockIdx.x * blockDim.x + threadIdx.x;
    if (e >= nnz) return;
    atomicAdd(cnt + i_idx[e], 1);
}

__global__ void scan_i_kernel(const int* __restrict__ cnt, int* __restrict__ rptr, int n) {
    __shared__ int partial[1024];
    int t = threadIdx.x;
    const int CH = (n + 1023) / 1024;
    int start = t * CH, end = min(start + CH, n);
    int s = 0;
    for (int k = start; k < end; ++k) s += cnt[k];
    partial[t] = s;
    __syncthreads();
    for (int off = 1; off < 1024; off <<= 1) {
        int v = (t >= off) ? partial[t - off] : 0;
        __syncthreads();
        partial[t] += v;
        __syncthreads();
    }
    int run = (t == 0) ? 0 : partial[t - 1];
    for (int k = start; k < end; ++k) { rptr[k] = run; run += cnt[k]; }
    if (t == 1023) rptr[n] = partial[1023];
}

__global__ void fill_i_kernel(const int* __restrict__ i_idx, const int* __restrict__ pi,
                              int* __restrict__ fill, int* __restrict__ eids, int nnz) {
    int e = blockIdx.x * blockDim.x + threadIdx.x;
    if (e >= nnz) return;
    int i = i_idx[e];
    int pos = atomicAdd(fill + i, 1);
    eids[pi[i] + pos] = e;
}

__global__ void gatherc_kernel(const int* __restrict__ eids, const int* __restrict__ u_idx,
                               int* __restrict__ col2, int nnz) {
    int t = blockIdx.x * blockDim.x + threadIdx.x;
    if (t < nnz) col2[t] = u_idx[eids[t]];
}

__global__ void gatherw_kernel(const int* __restrict__ eids, const float* __restrict__ sims,
                               float* __restrict__ w2, int nnz) {
    int t = blockIdx.x * blockDim.x + threadIdx.x;
    if (t < nnz) w2[t] = sims[eids[t]];
}

__global__ void diagi_kernel(const float* __restrict__ w2, const int* __restrict__ pi,
                             float* __restrict__ diag) {
    int i = blockIdx.x * blockDim.x + threadIdx.x;
    if (i >= N_ITEMS) return;
    float s = 0.f;
    int e = pi[i + 1];
    for (int k = pi[i]; k < e; ++k) s += w2[k];
    diag[N_USERS + i] = s;
}

// fp32 -> fp16, 8 elements per thread
__global__ void tohalf_kernel(const float* __restrict__ src, __half* __restrict__ dst, int n8) {
    int t = blockIdx.x * blockDim.x + threadIdx.x;
    if (t >= n8) return;
    const float4* s = (const float4*)(src + (size_t)t * 8);
    float4 a = s[0], b = s[1];
    H8 o;
    o.h[0] = __float2half(a.x); o.h[1] = __float2half(a.y);
    o.h[2] = __float2half(a.z); o.h[3] = __float2half(a.w);
    o.h[4] = __float2half(b.x); o.h[5] = __float2half(b.y);
    o.h[6] = __float2half(b.z); o.h[7] = __float2half(b.w);
    ((uint4*)dst)[t] = o.u;
}

// ---------------- embeddings (fused: emb + acc init + invnorm; fp16 gather) ----------------
// wave per row; 8 edge-groups x 8 lanes x 8 halves; 2-way unrolled
__global__ void emb_kernel(const __half* __restrict__ ulH, const __half* __restrict__ ilH,
                           const int* __restrict__ i_idx, const int* __restrict__ col2,
                           const int* __restrict__ pu, const int* __restrict__ pi,
                           __half* __restrict__ embH, float* __restrict__ acc,
                           float* __restrict__ invn) {
    int wid = (blockIdx.x * blockDim.x + threadIdx.x) >> 6;
    int lane = threadIdx.x & 63;
    if (wid >= N_TOTAL) return;
    int g = lane >> 3, c = lane & 7;
    float s[8];
    #pragma unroll
    for (int j = 0; j < 8; ++j) s[j] = 0.f;
    const __half* tbl; const int* cols; int b, e;
    if (wid < N_USERS) { tbl = ulH; cols = i_idx; b = pu[wid]; e = pu[wid + 1]; }
    else { int i = wid - N_USERS; tbl = ilH; cols = col2; b = pi[i]; e = pi[i + 1]; }
    int k = b + g;
    for (; k + 8 < e; k += 16) {
        H8 r0, r1;
        r0.u = ((const uint4*)(tbl + (size_t)cols[k] * D))[c];
        r1.u = ((const uint4*)(tbl + (size_t)cols[k + 8] * D))[c];
        #pragma unroll
        for (int j = 0; j < 8; ++j) s[j] += __half2float(r0.h[j]) + __half2float(r1.h[j]);
    }
    if (k < e) {
        H8 r0;
        r0.u = ((const uint4*)(tbl + (size_t)cols[k] * D))[c];
        #pragma unroll
        for (int j = 0; j < 8; ++j) s[j] += __half2float(r0.h[j]);
    }
    // reduce across the 8 edge-groups (lane bits 3,4,5)
    #pragma unroll
    for (int m = 8; m < 64; m <<= 1) {
        #pragma unroll
        for (int j = 0; j < 8; ++j) s[j] += __shfl_xor(s[j], m, 64);
    }
    // row sumsq across the 8 column lanes (bits 0..2)
    float nsq = 0.f;
    #pragma unroll
    for (int j = 0; j < 8; ++j) nsq += s[j] * s[j];
    #pragma unroll
    for (int m = 1; m < 8; m <<= 1) nsq += __shfl_xor(nsq, m, 64);
    if (g == 0) {
        H8 o;
        #pragma unroll
        for (int j = 0; j < 8; ++j) o.h[j] = __float2half(s[j]);
        ((uint4*)(embH + (size_t)wid * D))[c] = o.u;
        float4* ap = (float4*)(acc + (size_t)wid * D);
        ap[c * 2]     = make_float4(s[0], s[1], s[2], s[3]);
        ap[c * 2 + 1] = make_float4(s[4], s[5], s[6], s[7]);
        if (c == 0) invn[wid] = 1.f / fmaxf(sqrtf(nsq), 1e-8f);
    }
}

// ---------------- sims (wave per user; fused user diag; fp16 gather; no atomics) ----------------
__global__ void sims_kernel(const __half* __restrict__ embH, const float* __restrict__ invn,
                            const int* __restrict__ i_idx, const int* __restrict__ pu,
                            float* __restrict__ sims, float* __restrict__ diag) {
    int u = (blockIdx.x * blockDim.x + threadIdx.x) >> 6;
    int lane = threadIdx.x & 63;
    if (u >= N_USERS) return;
    int g = lane >> 3, c = lane & 7;
    float invu = invn[u];
    H8 ur; ur.u = ((const uint4*)(embH + (size_t)u * D))[c];
    float un[8];
    #pragma unroll
    for (int j = 0; j < 8; ++j) un[j] = __half2float(ur.h[j]) * invu;
    int b = pu[u], e = pu[u + 1];
    float dsum = 0.f;
    int k = b + g;
    for (; k + 8 < e; k += 16) {
        int i0 = i_idx[k], i1 = i_idx[k + 8];
        H8 r0, r1;
        r0.u = ((const uint4*)(embH + (size_t)(N_USERS + i0) * D))[c];
        r1.u = ((const uint4*)(embH + (size_t)(N_USERS + i1) * D))[c];
        float d0 = 0.f, d1 = 0.f;
        #pragma unroll
        for (int j = 0; j < 8; ++j) {
            d0 += un[j] * __half2float(r0.h[j]);
            d1 += un[j] * __half2float(r1.h[j]);
        }
        #pragma unroll
        for (int m = 1; m < 8; m <<= 1) { d0 += __shfl_xor(d0, m, 64); d1 += __shfl_xor(d1, m, 64); }
        if (c == 0) {
            float sv0 = (d0 * invn[N_USERS + i0] + 1.f) * 0.5f;
            float sv1 = (d1 * invn[N_USERS + i1] + 1.f) * 0.5f;
            sims[k] = sv0; sims[k + 8] = sv1;
            dsum += sv0 + sv1;
        }
    }
    if (k < e) {
        int i0 = i_idx[k];
        H8 r0;
        r0.u = ((const uint4*)(embH + (size_t)(N_USERS + i0) * D))[c];
        float d0 = 0.f;
        #pragma unroll
        for (int j = 0; j < 8; ++j) d0 += un[j] * __half2float(r0.h[j]);
        #pragma unroll
        for (int m = 1; m < 8; m <<= 1) d0 += __shfl_xor(d0, m, 64);
        if (c == 0) {
            float sv0 = (d0 * invn[N_USERS + i0] + 1.f) * 0.5f;
            sims[k] = sv0;
            dsum += sv0;
        }
    }
    // combine the 8 groups' partials (held on c==0 lanes)
    #pragma unroll
    for (int m = 8; m < 64; m <<= 1) dsum += __shfl_xor(dsum, m, 64);
    if (lane == 0) diag[u] = dsum;
}

// ---------------- propagation (fp16 gather, fp32 accumulate) ----------------
template <bool FINAL>
__global__ void prop_kernel(const __half* __restrict__ curH, __half* __restrict__ nextH,
                            float* __restrict__ acc, const float* __restrict__ sims,
                            const float* __restrict__ w2, const float* __restrict__ diag,
                            const int* __restrict__ i_idx, const int* __restrict__ col2,
                            const int* __restrict__ pu, const int* __restrict__ pi) {
    int wid = (blockIdx.x * blockDim.x + threadIdx.x) >> 6;
    int lane = threadIdx.x & 63;
    if (wid >= N_TOTAL) return;
    int g = lane >> 3, c = lane & 7;
    float s[8];
    #pragma unroll
    for (int j = 0; j < 8; ++j) s[j] = 0.f;
    const int* cols; const float* ws; int b, e, colOff;
    if (wid < N_USERS) { b = pu[wid]; e = pu[wid + 1]; cols = i_idx; ws = sims; colOff = N_USERS; }
    else { int i = wid - N_USERS; b = pi[i]; e = pi[i + 1]; cols = col2; ws = w2; colOff = 0; }
    int k = b + g;
    for (; k + 8 < e; k += 16) {
        float w0 = ws[k], w1 = ws[k + 8];
        H8 r0, r1;
        r0.u = ((const uint4*)(curH + (size_t)(cols[k] + colOff) * D))[c];
        r1.u = ((const uint4*)(curH + (size_t)(cols[k + 8] + colOff) * D))[c];
        #pragma unroll
        for (int j = 0; j < 8; ++j) s[j] += w0 * __half2float(r0.h[j]) + w1 * __half2float(r1.h[j]);
    }
    if (k < e) {
        float w0 = ws[k];
        H8 r0;
        r0.u = ((const uint4*)(curH + (size_t)(cols[k] + colOff) * D))[c];
        #pragma unroll
        for (int j = 0; j < 8; ++j) s[j] += w0 * __half2float(r0.h[j]);
    }
    #pragma unroll
    for (int m = 8; m < 64; m <<= 1) {
        #pragma unroll
        for (int j = 0; j < 8; ++j) s[j] += __shfl_xor(s[j], m, 64);
    }
    if (g == 0) {
        float invd = 1.f / (diag[wid] + 1e-7f);
        float v[8];
        #pragma unroll
        for (int j = 0; j < 8; ++j) v[j] = s[j] * invd;
        float4* ap = (float4*)(acc + (size_t)wid * D);
        float4 a0 = ap[c * 2], a1 = ap[c * 2 + 1];
        if (FINAL) {
            a0.x = (a0.x + v[0]) * 0.25f; a0.y = (a0.y + v[1]) * 0.25f;
            a0.z = (a0.z + v[2]) * 0.25f; a0.w = (a0.w + v[3]) * 0.25f;
            a1.x = (a1.x + v[4]) * 0.25f; a1.y = (a1.y + v[5]) * 0.25f;
            a1.z = (a1.z + v[6]) * 0.25f; a1.w = (a1.w + v[7]) * 0.25f;
        } else {
            H8 o;
            #pragma unroll
            for (int j = 0; j < 8; ++j) o.h[j] = __float2half(v[j]);
            ((uint4*)(nextH + (size_t)wid * D))[c] = o.u;
            a0.x += v[0]; a0.y += v[1]; a0.z += v[2]; a0.w += v[3];
            a1.x += v[4]; a1.y += v[5]; a1.z += v[6]; a1.w += v[7];
        }
        ap[c * 2] = a0; ap[c * 2 + 1] = a1;
    }
}

// ---------------- launch ----------------

extern "C" void kernel_launch(void* const* d_in, const int* in_sizes, int n_in,
                              void* d_out, int out_size, void* d_ws, size_t ws_size,
                              hipStream_t stream) {
    const float* user_linear = (const float*)d_in[0];
    const float* item_linear = (const float*)d_in[1];
    const int* u_idx = (const int*)d_in[2];
    const int* i_idx = (const int*)d_in[3];
    const int nnz = in_sizes[2];

    // carve workspace (256B aligned)
    char* p = (char*)d_ws;
    auto carve = [&](size_t bytes) { void* r = (void*)p; p += (bytes + 255) & ~(size_t)255; return r; };
    __half* embA = (__half*)carve((size_t)N_TOTAL * D * 2);
    __half* embB = (__half*)carve((size_t)N_TOTAL * D * 2);
    __half* ulH  = (__half*)carve((size_t)N_ITEMS * D * 2);
    __half* ilH  = (__half*)carve((size_t)N_USERS * D * 2);
    float* sims = (float*)carve((size_t)nnz * 4);
    float* w2   = (float*)carve((size_t)nnz * 4);
    float* diag = (float*)carve((size_t)N_TOTAL * 4);
    float* invn = (float*)carve((size_t)N_TOTAL * 4);
    int* pu   = (int*)carve((size_t)(N_USERS + 1) * 4);
    int* pi   = (int*)carve((size_t)(N_ITEMS + 1) * 4);
    int* eids = (int*)carve((size_t)nnz * 4);
    int* col2 = (int*)carve((size_t)nnz * 4);
    int* cnt  = (int*)carve((size_t)N_ITEMS * 4);

    float* acc = (float*)d_out;  // [N_TOTAL, D]

    const int B = 256;

    // CSR build + input fp16 conversion
    hipMemsetAsync(cnt, 0, (size_t)N_ITEMS * 4, stream);
    rowptr_u_kernel<<<(N_USERS + 1 + B - 1) / B, B, 0, stream>>>(u_idx, pu, nnz);
    count_i_kernel<<<(nnz + B - 1) / B, B, 0, stream>>>(i_idx, cnt, nnz);
    tohalf_kernel<<<((N_ITEMS * D / 8) + B - 1) / B, B, 0, stream>>>(user_linear, ulH, N_ITEMS * D / 8);
    tohalf_kernel<<<((N_USERS * D / 8) + B - 1) / B, B, 0, stream>>>(item_linear, ilH, N_USERS * D / 8);
    scan_i_kernel<<<1, 1024, 0, stream>>>(cnt, pi, N_ITEMS);
    hipMemsetAsync(cnt, 0, (size_t)N_ITEMS * 4, stream);
    fill_i_kernel<<<(nnz + B - 1) / B, B, 0, stream>>>(i_idx, pi, cnt, eids, nnz);
    gatherc_kernel<<<(nnz + B - 1) / B, B, 0, stream>>>(eids, u_idx, col2, nnz);

    // embeddings (+acc init, +invnorm)
    int rowWaveThreads = N_TOTAL * 64;
    emb_kernel<<<(rowWaveThreads + B - 1) / B, B, 0, stream>>>(ulH, ilH, i_idx, col2,
                                                              pu, pi, embA, acc, invn);

    // sims (wave per user; writes user diag) then item diag from w2
    long long simThreads = (long long)N_USERS * 64;
    sims_kernel<<<(int)((simThreads + B - 1) / B), B, 0, stream>>>(embA, invn, i_idx, pu, sims, diag);
    gatherw_kernel<<<(nnz + B - 1) / B, B, 0, stream>>>(eids, sims, w2, nnz);
    diagi_kernel<<<(N_ITEMS + B - 1) / B, B, 0, stream>>>(w2, pi, diag);

    // 3 propagation layers; final one folds the mean (x0.25)
    prop_kernel<false><<<(rowWaveThreads + B - 1) / B, B, 0, stream>>>(embA, embB, acc, sims, w2, diag,
                                                                      i_idx, col2, pu, pi);
    prop_kernel<false><<<(rowWaveThreads + B - 1) / B, B, 0, stream>>>(embB, embA, acc, sims, w2, diag,
                                                                      i_idx, col2, pu, pi);
    prop_kernel<true><<<(rowWaveThreads + B - 1) / B, B, 0, stream>>>(embA, embB, acc, sims, w2, diag,
                                                                     i_idx, col2, pu, pi);
}